// Round 13
// baseline (646.585 us; speedup 1.0000x reference)
//
#include <hip/hip_runtime.h>
#include <hip/hip_fp16.h>
#include <hip/hip_cooperative_groups.h>

namespace cg = cooperative_groups;

#define NN 100000   // nodes
#define NE 3200000  // edges
#define NF 128      // in features
#define EM 20       // embed
#define NC 10       // classes
#define NG 64       // graphs

#define NB 782      // dst buckets of 128 nodes
#define CAPB 4608   // per-bucket capacity
#define T 4096      // edges per scatter tile
#define NTILES ((NE + T - 1) / T)   // 782
#define XTILES ((NN + 63) / 64)     // 1563
#define BLK 512

// ---- LDS union (bytes). Max phase = scatter: 53,312 B ----
#define L_CNT    0        // u32[1024]
#define L_OFF    4096     // u32[1024]
#define L_GBASE  8192     // u32[1024] (782 used)
#define L_WSUM   12288    // u32[16]
#define L_STAGED 12352    // u64[4096] (32768 B); first 4 KB aliased as scan scratch
#define L_BKT    45120    // u16[4096] (8192 B)
// sortaggr layout: srt u64[4608]@0 (36864) | cnt u32[128]@36864 | off u32[128]@37376 | rank u16[4608]@37888 | wtot u32@47104
#define S_SRT    0
#define S_CNT    36864
#define S_OFF    37376
#define S_RANK   37888
#define S_WTOT   47104
// xw layout: Ws f32[2560]@0 | xs f32[64*129]@10240  (total 43,264)
#define X_WS     0
#define X_XS     10240

__device__ inline void unpack16(uint4 a0, uint4 a1, float* f) {
    const __half2* h = (const __half2*)&a0;
#pragma unroll
    for (int c = 0; c < 4; ++c) { float2 t = __half22float2(h[c]); f[2*c] = t.x; f[2*c+1] = t.y; }
    h = (const __half2*)&a1;
#pragma unroll
    for (int c = 0; c < 4; ++c) { float2 t = __half22float2(h[c]); f[8+2*c] = t.x; f[9+2*c] = t.y; }
}
__device__ inline void unpack4(uint2 b0, float* f) {
    const __half2* h = (const __half2*)&b0;
#pragma unroll
    for (int c = 0; c < 2; ++c) { float2 t = __half22float2(h[c]); f[2*c] = t.x; f[2*c+1] = t.y; }
}
__device__ inline int lbound(const int* __restrict__ batch, int key) {
    int lo = 0, hi = NN;
    while (lo < hi) {
        int mid = (lo + hi) >> 1;
        if (batch[mid] < key) lo = mid + 1; else hi = mid;
    }
    return lo;
}

__global__ __launch_bounds__(BLK) void k_fused(
        const int* __restrict__ src, const int* __restrict__ dst,
        const float* __restrict__ ew, const float* __restrict__ x,
        const float* __restrict__ W, const float* __restrict__ b,
        const float* __restrict__ lw, const float* __restrict__ lb,
        const int* __restrict__ batch, float* __restrict__ out,
        int* __restrict__ gcursor, float* __restrict__ dinv,
        __half* __restrict__ xwhA, __half* __restrict__ xwhB,
        float* __restrict__ embed, unsigned long long* __restrict__ barr) {
    cg::grid_group grid = cg::this_grid();
    __shared__ __align__(16) unsigned char L[53312];
    int tid = threadIdx.x;

    // ---------------- P0: zero gcursor ----------------
    if (blockIdx.x == 0)
        for (int i = tid; i < 1024; i += BLK) gcursor[i] = 0;
    grid.sync();

    // ---------------- P1: bucketed counting-sort scatter (round-8/9 proven body) ----------------
    {
        unsigned int* cnt   = (unsigned int*)(L + L_CNT);
        unsigned int* off   = (unsigned int*)(L + L_OFF);
        unsigned int* gbase = (unsigned int*)(L + L_GBASE);
        unsigned long long* staged = (unsigned long long*)(L + L_STAGED);
        unsigned short* bkt = (unsigned short*)(L + L_BKT);
        unsigned int* scratch = (unsigned int*)staged;   // disjoint phases
        for (int tile = blockIdx.x; tile < NTILES; tile += gridDim.x) {
            long E0 = (long)tile * T;
            int tot = (int)min((long)T, (long)NE - E0);
            for (int i = tid; i < 1024; i += BLK) { cnt[i] = 0; scratch[i] = 0; }
            __syncthreads();
            for (int k = 0; k < T / BLK; ++k) {
                int e = k * BLK + tid;
                if (e < tot) atomicAdd(&cnt[((unsigned)dst[E0 + e]) >> 7], 1u);
            }
            __syncthreads();
            for (int i = tid; i < 1024; i += BLK) scratch[i] = cnt[i];
            __syncthreads();
            for (int d = 1; d < 1024; d <<= 1) {
                unsigned int v[2];
#pragma unroll
                for (int q = 0; q < 2; ++q) {
                    int idx = q * BLK + tid;
                    v[q] = (idx >= d) ? scratch[idx - d] : 0u;
                }
                __syncthreads();
#pragma unroll
                for (int q = 0; q < 2; ++q) scratch[q * BLK + tid] += v[q];
                __syncthreads();
            }
            for (int i = tid; i < 1024; i += BLK) off[i] = scratch[i] - cnt[i];
            __syncthreads();
            for (int i = tid; i < NB; i += BLK) {
                unsigned int c = cnt[i];
                gbase[i] = c ? (unsigned int)atomicAdd(&gcursor[i], (int)c) : 0u;
                cnt[i] = 0;
            }
            __syncthreads();
            for (int k = 0; k < T / BLK; ++k) {
                int e = k * BLK + tid;
                if (e < tot) {
                    long ge = E0 + e;
                    unsigned int d = (unsigned)dst[ge];
                    unsigned int bb = d >> 7;
                    unsigned int slot = atomicAdd(&cnt[bb], 1u);
                    unsigned int pos = off[bb] + slot;
                    unsigned long long rec = ((unsigned long long)__float_as_uint(ew[ge]) << 32)
                                           | ((((unsigned)src[ge]) << 7) | (d & 127u));
                    staged[pos] = rec;
                    bkt[pos] = (unsigned short)bb;
                }
            }
            __syncthreads();
            for (int i = tid; i < tot; i += BLK) {
                unsigned int bb = bkt[i];
                unsigned int gpos = gbase[bb] + ((unsigned)i - off[bb]);
                if (gpos < CAPB) barr[(size_t)bb * CAPB + gpos] = staged[i];
            }
            __syncthreads();   // next tile reuses cnt/scratch/staged
        }
    }
    __threadfence();
    grid.sync();

    // ---------------- P2: weighted degree -> dinv (round-10 proven body) ----------------
    {
        float* dacc = (float*)L;
        for (int bk = blockIdx.x; bk < NB; bk += gridDim.x) {
            if (tid < 128) dacc[tid] = 0.f;
            __syncthreads();
            int cntb = min(gcursor[bk], CAPB);
            const unsigned long long* row = barr + (size_t)bk * CAPB;
            for (int i = tid; i < cntb; i += BLK) {
                unsigned long long r = row[i];
                atomicAdd(&dacc[(unsigned)r & 127u], __uint_as_float((unsigned)(r >> 32)));
            }
            __syncthreads();
            if (tid < 128) {
                int gd = bk * 128 + tid;
                if (gd < NN) dinv[gd] = rsqrtf(1.0f + dacc[tid]);  // +1 = self-loop
            }
            __syncthreads();
        }
    }
    __threadfence();
    grid.sync();

    // ---------------- P3: xw = x@W -> dinv-prescaled split fp16 planes (round-12 body, tid<256 compute) ----------------
    {
        float* Ws = (float*)(L + X_WS);
        float* xs = (float*)(L + X_XS);
        for (int i = tid; i < NF * EM; i += BLK) Ws[i] = W[i];
        for (int t = blockIdx.x; t < XTILES; t += gridDim.x) {
            int base = t * 64;
            __syncthreads();   // previous tile's compute done before overwriting xs
            const float4* xg = (const float4*)(x + (size_t)base * NF);
            for (int v = tid; v < 64 * NF / 4; v += BLK) {
                int fidx = v * 4;
                size_t gidx = (size_t)base * NF + fidx;
                float4 val = (gidx + 3 < (size_t)NN * NF) ? xg[v] : make_float4(0.f, 0.f, 0.f, 0.f);
                int r = fidx / NF, c = fidx % NF;
                float* p = xs + r * 129 + c;
                p[0] = val.x; p[1] = val.y; p[2] = val.z; p[3] = val.w;
            }
            __syncthreads();
            if (tid < 256) {
                int n = tid & 63;
                int jg = tid >> 6;       // 0..3 -> dims jg*5..jg*5+4
                int j0 = jg * 5;
                if (base + n < NN) {
                    float acc[5] = {0.f, 0.f, 0.f, 0.f, 0.f};
                    const float* xr = xs + n * 129;
#pragma unroll 4
                    for (int k = 0; k < NF; ++k) {
                        float xv = xr[k];
                        const float* wr = Ws + k * EM + j0;
#pragma unroll
                        for (int jj = 0; jj < 5; ++jj) acc[jj] = fmaf(xv, wr[jj], acc[jj]);
                    }
                    float dv = dinv[base + n];
#pragma unroll
                    for (int jj = 0; jj < 5; ++jj) {
                        int j = j0 + jj;
                        __half hv = __float2half(acc[jj] * dv);
                        if (j < 16) xwhA[(size_t)(base + n) * 16 + j] = hv;
                        else        xwhB[(size_t)(base + n) * 4 + (j - 16)] = hv;
                    }
                }
            }
        }
    }
    __threadfence();
    grid.sync();

    // ---------------- P4: LDS dl-sort + gather-aggregate + epilogue (round-10 body, rank in LDS) ----------------
    {
        unsigned long long* srt = (unsigned long long*)(L + S_SRT);
        unsigned int* cnt2 = (unsigned int*)(L + S_CNT);
        unsigned int* off2 = (unsigned int*)(L + S_OFF);
        unsigned short* rank = (unsigned short*)(L + S_RANK);
        unsigned int* wtot = (unsigned int*)(L + S_WTOT);
        const uint4* pA = (const uint4*)xwhA;
        const uint2* pB = (const uint2*)xwhB;
        for (int bk = blockIdx.x; bk < NB; bk += gridDim.x) {
            if (tid < 128) cnt2[tid] = 0;
            __syncthreads();
            int cntb = min(gcursor[bk], CAPB);
            const unsigned long long* row = barr + (size_t)bk * CAPB;
            for (int e = tid; e < cntb; e += BLK)
                rank[e] = (unsigned short)atomicAdd(&cnt2[(unsigned)row[e] & 127u], 1u);
            __syncthreads();
            // inclusive scan of cnt2[0..128) via two-wave shfl (round-10 proven)
            unsigned int v = 0, s = 0;
            if (tid < 128) {
                v = cnt2[tid]; s = v;
#pragma unroll
                for (int o = 1; o < 64; o <<= 1) {
                    unsigned int t2 = __shfl_up(s, o);
                    if ((tid & 63) >= o) s += t2;
                }
                if (tid == 63) *wtot = s;
            }
            __syncthreads();
            if (tid < 128) {
                if (tid >= 64) s += *wtot;
                off2[tid] = s;              // inclusive end of run
            }
            __syncthreads();
            // scatter into sorted LDS order (re-read row: L2-hot)
            for (int e = tid; e < cntb; e += BLK) {
                unsigned long long r = row[e];
                unsigned int dl = (unsigned)r & 127u;
                srt[off2[dl] - cnt2[dl] + rank[e]] = r;
            }
            __syncthreads();
            // aggregate: 4 threads per dst
            int d = tid >> 2, sub = tid & 3;
            int s0 = (int)(off2[d] - cnt2[d]), s1 = (int)off2[d];
            float acc[20];
#pragma unroll
            for (int j = 0; j < 20; ++j) acc[j] = 0.f;
            for (int e = s0 + sub; e < s1; e += 4) {
                unsigned long long r = srt[e];
                unsigned int sN = ((unsigned)r) >> 7;
                float nw = __uint_as_float((unsigned)(r >> 32));  // raw edge weight
                uint4 a0 = pA[(size_t)sN * 2];
                uint4 a1 = pA[(size_t)sN * 2 + 1];
                uint2 b0 = pB[sN];
                float f[20];
                unpack16(a0, a1, f);
                unpack4(b0, f + 16);
#pragma unroll
                for (int j = 0; j < 20; ++j) acc[j] = fmaf(f[j], nw, acc[j]);
            }
#pragma unroll
            for (int j = 0; j < 20; ++j) {
                acc[j] += __shfl_xor(acc[j], 1);
                acc[j] += __shfl_xor(acc[j], 2);
            }
            if (sub == 0) {
                int gd = bk * 128 + d;
                if (gd < NN) {
                    float dv = dinv[gd];
                    uint4 a0 = pA[(size_t)gd * 2];
                    uint4 a1 = pA[(size_t)gd * 2 + 1];
                    uint2 b0 = pB[gd];
                    float xdh[20];
                    unpack16(a0, a1, xdh);
                    unpack4(b0, xdh + 16);   // = xw[gd][:]*dinv[gd]
                    float r[20];
                    float ss = 0.f;
#pragma unroll
                    for (int j = 0; j < 20; ++j) {
                        r[j] = dv * (acc[j] + xdh[j]) + b[j];
                        ss = fmaf(r[j], r[j], ss);
                    }
                    float inv = 1.0f / fmaxf(sqrtf(ss), 1e-12f);
                    float4 o4[5];
                    float* o = (float*)o4;
#pragma unroll
                    for (int j = 0; j < 20; ++j) {
                        float e2 = r[j] * inv;
                        o[j] = e2 > 0.f ? e2 : 0.f;
                    }
                    float4* eo = (float4*)(embed + (size_t)gd * EM);
#pragma unroll
                    for (int c = 0; c < 5; ++c) eo[c] = o4[c];
                }
            }
            __syncthreads();   // next bucket reuses srt/cnt2/off2/rank
        }
    }
    __threadfence();
    grid.sync();

    // ---------------- P5: per-graph pool (max+mean) + final linear (round-10 body, tid<256) ----------------
    {
        float (*cross)[40] = (float(*)[40])L;
        float* pooled = (float*)(L + 4 * 40 * 4);
        for (int g = blockIdx.x; g < NG; g += gridDim.x) {
            int s0 = lbound(batch, g), s1 = lbound(batch, g + 1);
            int cntg = s1 - s0;
            if (tid < 256) {
                float mx[EM], sm[EM];
#pragma unroll
                for (int j = 0; j < EM; ++j) { mx[j] = 0.f; sm[j] = 0.f; }
                for (int n = s0 + tid; n < s1; n += 256) {
                    const float4* e = (const float4*)(embed + (size_t)n * EM);
#pragma unroll
                    for (int c = 0; c < 5; ++c) {
                        float4 v = e[c];
                        int j = c * 4;
                        mx[j+0] = fmaxf(mx[j+0], v.x); sm[j+0] += v.x;
                        mx[j+1] = fmaxf(mx[j+1], v.y); sm[j+1] += v.y;
                        mx[j+2] = fmaxf(mx[j+2], v.z); sm[j+2] += v.z;
                        mx[j+3] = fmaxf(mx[j+3], v.w); sm[j+3] += v.w;
                    }
                }
#pragma unroll
                for (int o = 32; o > 0; o >>= 1) {
#pragma unroll
                    for (int j = 0; j < EM; ++j) {
                        mx[j] = fmaxf(mx[j], __shfl_xor(mx[j], o));
                        sm[j] += __shfl_xor(sm[j], o);
                    }
                }
                int wave = tid >> 6, lane = tid & 63;
                if (lane == 0) {
#pragma unroll
                    for (int j = 0; j < EM; ++j) { cross[wave][j] = mx[j]; cross[wave][EM + j] = sm[j]; }
                }
            }
            __syncthreads();
            if (tid < 40) {
                int j = tid;
                float v = cross[0][j];
                if (j < EM) v = fmaxf(fmaxf(v, cross[1][j]), fmaxf(cross[2][j], cross[3][j]));
                else        v = v + cross[1][j] + cross[2][j] + cross[3][j];
                if (j >= EM) v *= 1.0f / fmaxf((float)cntg, 1.0f);
                pooled[j] = v;
            }
            __syncthreads();
            if (tid < NC) {
                int c = tid;
                float acc = lb[c];
#pragma unroll
                for (int j = 0; j < 2 * EM; ++j) acc = fmaf(pooled[j], lw[j * NC + c], acc);
                out[g * NC + c] = acc;
            }
            __syncthreads();
        }
    }
}

static inline size_t align_up(size_t v) { return (v + 1023) & ~(size_t)1023; }

extern "C" void kernel_launch(void* const* d_in, const int* in_sizes, int n_in,
                              void* d_out, int out_size, void* d_ws, size_t ws_size,
                              hipStream_t stream) {
    const int*   ei    = (const int*)d_in[1];
    const int*   srcp  = ei;
    const int*   dstp  = ei + NE;
    const float* x     = (const float*)d_in[0];
    const float* ew    = (const float*)d_in[2];
    const int*   batch = (const int*)d_in[3];
    const float* W     = (const float*)d_in[4];
    const float* b     = (const float*)d_in[5];
    const float* lw    = (const float*)d_in[6];
    const float* lb    = (const float*)d_in[7];
    float* out = (float*)d_out;

    char* ws = (char*)d_ws;
    int*    gcursor = (int*)ws;    ws += align_up(4096);
    float*  dinv    = (float*)ws;  ws += align_up((size_t)NN * 4);
    __half* xwhA    = (__half*)ws; ws += align_up((size_t)NN * 16 * 2);
    __half* xwhB    = (__half*)ws; ws += align_up((size_t)NN * 4 * 2);
    float*  embed   = (float*)ws;  ws += align_up((size_t)NN * EM * 4);
    unsigned long long* barr64 = (unsigned long long*)ws;   // NB*CAPB*8 = 28.8 MB

    int occ = 0;
    (void)hipOccupancyMaxActiveBlocksPerMultiprocessor(&occ, k_fused, BLK, 0);
    if (occ < 1) occ = 1;
    int grid = occ * 256;            // 256 CUs on MI355X
    if (grid > 2048) grid = 2048;

    void* args[] = { (void*)&srcp, (void*)&dstp, (void*)&ew, (void*)&x,
                     (void*)&W, (void*)&b, (void*)&lw, (void*)&lb,
                     (void*)&batch, (void*)&out,
                     (void*)&gcursor, (void*)&dinv, (void*)&xwhA, (void*)&xwhB,
                     (void*)&embed, (void*)&barr64 };
    (void)hipLaunchCooperativeKernel((const void*)k_fused, dim3(grid), dim3(BLK),
                                     args, 0, stream);
}

// Round 14
// 265.653 us; speedup vs baseline: 2.4339x; 2.4339x over previous
//
#include <hip/hip_runtime.h>
#include <hip/hip_fp16.h>

#define NN 100000   // nodes
#define NE 3200000  // edges
#define NF 128      // in features
#define EM 20       // embed
#define NC 10       // classes
#define NG 64       // graphs

#define NB 782      // dst buckets of 128 nodes
#define CAPB 4608   // per-bucket capacity (mean 4096, +8 sigma)
#define T 4096      // edges per scatter block
#define SBLK 1024   // scatter block threads

// ---------------- bucketed counting-sort scatter (round-10 proven) ----------------
__global__ __launch_bounds__(SBLK) void k_scatter(
        const int* __restrict__ src, const int* __restrict__ dst,
        const float* __restrict__ w, int* __restrict__ gcursor,
        uint2* __restrict__ barr) {
    __shared__ unsigned int cnt[1024];
    __shared__ unsigned int off[1024];
    __shared__ unsigned int gbase[NB];
    __shared__ unsigned int wsum[16];
    __shared__ uint2 staged[T];
    __shared__ unsigned short bkt[T];
    int tid = threadIdx.x;
    long E0 = (long)blockIdx.x * T;
    int tot = (int)min((long)T, (long)NE - E0);
    cnt[tid] = 0;
    __syncthreads();
    // histogram; cache dst in VGPRs
    unsigned int dreg[T / SBLK];
#pragma unroll
    for (int k = 0; k < T / SBLK; ++k) {
        int e = k * SBLK + tid;
        dreg[k] = 0;
        if (e < tot) {
            dreg[k] = (unsigned)dst[E0 + e];
            atomicAdd(&cnt[dreg[k] >> 7], 1u);
        }
    }
    __syncthreads();
    // exclusive scan of cnt[0..1024) via wave shfl
    {
        int lane = tid & 63, wv = tid >> 6;
        unsigned int v = cnt[tid];
        unsigned int s = v;
#pragma unroll
        for (int o = 1; o < 64; o <<= 1) {
            unsigned int t = __shfl_up(s, o);
            if (lane >= o) s += t;
        }
        if (lane == 63) wsum[wv] = s;
        __syncthreads();
        if (tid == 0) {
            unsigned int a = 0;
#pragma unroll
            for (int i = 0; i < 16; ++i) { unsigned int t = wsum[i]; wsum[i] = a; a += t; }
        }
        __syncthreads();
        off[tid] = wsum[wv] + s - v;   // exclusive prefix
    }
    __syncthreads();
    // reserve global segments; reset cnt as running slot counter
    if (tid < NB) {
        unsigned int c = cnt[tid];
        gbase[tid] = c ? (unsigned int)atomicAdd(&gcursor[tid], (int)c) : 0u;
        cnt[tid] = 0;
    }
    __syncthreads();
    // stage records grouped by bucket
#pragma unroll
    for (int k = 0; k < T / SBLK; ++k) {
        int e = k * SBLK + tid;
        if (e < tot) {
            long ge = E0 + e;
            unsigned int d = dreg[k];
            unsigned int b = d >> 7;
            unsigned int slot = atomicAdd(&cnt[b], 1u);
            unsigned int pos = off[b] + slot;
            staged[pos] = make_uint2((((unsigned)src[ge]) << 7) | (d & 127u),
                                     __float_as_uint(w[ge]));
            bkt[pos] = (unsigned short)b;
        }
    }
    __syncthreads();
    // coalesced run-flush
    for (int i = tid; i < tot; i += SBLK) {
        unsigned int b = bkt[i];
        unsigned int gpos = gbase[b] + ((unsigned)i - off[b]);
        if (gpos < CAPB) barr[(size_t)b * CAPB + gpos] = staged[i];
    }
}

// ---------------- weighted degree -> dinv (per bucket, LDS atomics) ----------------
__global__ void k_degb(const int* __restrict__ gcursor, const uint2* __restrict__ barr,
                       float* __restrict__ dinv) {
    __shared__ float dacc[128];
    int bk = blockIdx.x, tid = threadIdx.x;
    if (tid < 128) dacc[tid] = 0.f;
    __syncthreads();
    int cntb = min(gcursor[bk], CAPB);
    const uint2* row = barr + (size_t)bk * CAPB;
    for (int i = tid; i < cntb; i += 1024) {
        uint2 r = row[i];
        atomicAdd(&dacc[r.x & 127u], __uint_as_float(r.y));
    }
    __syncthreads();
    if (tid < 128) {
        int gd = bk * 128 + tid;
        if (gd < NN) dinv[gd] = rsqrtf(1.0f + dacc[tid]);  // +1 = self-loop
    }
}

// ---------------- xw = x @ W -> dinv-prescaled split fp16 planes ----------------
// planeA: dims 0-15, 32B/node (line-aligned). planeB: dims 16-19, 8B/node.
__global__ void k_xw(const float* __restrict__ x, const float* __restrict__ W,
                     const float* __restrict__ dinv,
                     __half* __restrict__ xwhA, __half* __restrict__ xwhB) {
    __shared__ float xs[64 * 129];
    __shared__ float Ws[NF * EM];
    int base = blockIdx.x * 64;
    for (int i = threadIdx.x; i < NF * EM; i += 256) Ws[i] = W[i];
    const float4* xg = (const float4*)(x + (size_t)base * NF);
    for (int v = threadIdx.x; v < 64 * NF / 4; v += 256) {
        int fidx = v * 4;
        size_t gidx = (size_t)base * NF + fidx;
        float4 val = (gidx + 3 < (size_t)NN * NF) ? xg[v] : make_float4(0.f, 0.f, 0.f, 0.f);
        int r = fidx / NF, c = fidx % NF;
        float* p = xs + r * 129 + c;
        p[0] = val.x; p[1] = val.y; p[2] = val.z; p[3] = val.w;
    }
    __syncthreads();
    int n = threadIdx.x & 63;
    int jg = threadIdx.x >> 6;       // 0..3 -> dims jg*5..jg*5+4
    int j0 = jg * 5;
    if (base + n >= NN) return;
    float acc[5] = {0.f, 0.f, 0.f, 0.f, 0.f};
    const float* xr = xs + n * 129;
#pragma unroll 4
    for (int k = 0; k < NF; ++k) {
        float xv = xr[k];
        const float* wr = Ws + k * EM + j0;
#pragma unroll
        for (int jj = 0; jj < 5; ++jj) acc[jj] = fmaf(xv, wr[jj], acc[jj]);
    }
    float dv = dinv[base + n];
#pragma unroll
    for (int jj = 0; jj < 5; ++jj) {
        int j = j0 + jj;
        __half hv = __float2half(acc[jj] * dv);
        if (j < 16) xwhA[(size_t)(base + n) * 16 + j] = hv;
        else        xwhB[(size_t)(base + n) * 4 + (j - 16)] = hv;
    }
}

__device__ inline void unpack16(uint4 a0, uint4 a1, float* f) {
    const __half2* h = (const __half2*)&a0;
#pragma unroll
    for (int c = 0; c < 4; ++c) { float2 t = __half22float2(h[c]); f[2*c] = t.x; f[2*c+1] = t.y; }
    h = (const __half2*)&a1;
#pragma unroll
    for (int c = 0; c < 4; ++c) { float2 t = __half22float2(h[c]); f[8+2*c] = t.x; f[9+2*c] = t.y; }
}
__device__ inline void unpack4(uint2 b0, float* f) {
    const __half2* h = (const __half2*)&b0;
#pragma unroll
    for (int c = 0; c < 2; ++c) { float2 t = __half22float2(h[c]); f[2*c] = t.x; f[2*c+1] = t.y; }
}

// ---------------- fused: LDS dl-sort + gather-aggregate + epilogue ----------------
// 512 threads. Sort bucket records in LDS (1 int atomic/edge), then 4 thr/dst
// aggregate straight from LDS (records never re-read from HBM during gather),
// fused self-loop + bias + L2norm + ReLU.
__global__ void k_sortaggr(const int* __restrict__ gcursor,
                           const unsigned long long* __restrict__ barr64,
                           const __half* __restrict__ xwhA, const __half* __restrict__ xwhB,
                           const float* __restrict__ dinv, const float* __restrict__ b,
                           float* __restrict__ embed) {
    __shared__ unsigned long long srt[CAPB];   // 36.9 KB
    __shared__ unsigned int cnt[128];
    __shared__ unsigned int off[128];
    __shared__ unsigned int wtot;
    int bk = blockIdx.x, tid = threadIdx.x;
    if (tid < 128) cnt[tid] = 0;
    __syncthreads();
    int cntb = min(gcursor[bk], CAPB);
    const unsigned long long* row = barr64 + (size_t)bk * CAPB;
    unsigned long long rec[9];
    unsigned int pos[9];
    int K = 0;
    for (int e = tid; e < cntb; e += 512) {
        rec[K] = row[e];
        pos[K] = atomicAdd(&cnt[(unsigned)rec[K] & 127u], 1u);
        ++K;
    }
    __syncthreads();
    // inclusive scan of cnt[0..128) via two-wave shfl
    unsigned int v = 0, s = 0;
    if (tid < 128) {
        v = cnt[tid]; s = v;
#pragma unroll
        for (int o = 1; o < 64; o <<= 1) {
            unsigned int t = __shfl_up(s, o);
            if ((tid & 63) >= o) s += t;
        }
        if (tid == 63) wtot = s;
    }
    __syncthreads();
    if (tid < 128) {
        if (tid >= 64) s += wtot;
        off[tid] = s;              // inclusive end of run
    }
    __syncthreads();
    // scatter into sorted LDS order
    for (int k = 0; k < K; ++k) {
        unsigned int dl = (unsigned)rec[k] & 127u;
        srt[off[dl] - cnt[dl] + pos[k]] = rec[k];
    }
    __syncthreads();
    // aggregate: 4 threads per dst, records from LDS, gathers from split plane
    int d = tid >> 2, sub = tid & 3;
    int s0 = (int)(off[d] - cnt[d]), s1 = (int)off[d];
    const uint4* pA = (const uint4*)xwhA;
    const uint2* pB = (const uint2*)xwhB;
    float acc[20];
#pragma unroll
    for (int j = 0; j < 20; ++j) acc[j] = 0.f;
    for (int e = s0 + sub; e < s1; e += 4) {
        unsigned long long r = srt[e];
        unsigned int sN = ((unsigned int)r) >> 7;
        float nw = __uint_as_float((unsigned int)(r >> 32));  // raw edge weight
        uint4 a0 = pA[(size_t)sN * 2];
        uint4 a1 = pA[(size_t)sN * 2 + 1];
        uint2 b0 = pB[sN];
        float f[20];
        unpack16(a0, a1, f);
        unpack4(b0, f + 16);
#pragma unroll
        for (int j = 0; j < 20; ++j) acc[j] = fmaf(f[j], nw, acc[j]);
    }
#pragma unroll
    for (int j = 0; j < 20; ++j) {
        acc[j] += __shfl_xor(acc[j], 1);
        acc[j] += __shfl_xor(acc[j], 2);
    }
    if (sub == 0) {
        int gd = bk * 128 + d;
        if (gd < NN) {
            float dv = dinv[gd];
            uint4 a0 = pA[(size_t)gd * 2];
            uint4 a1 = pA[(size_t)gd * 2 + 1];
            uint2 b0 = pB[gd];
            float xdh[20];
            unpack16(a0, a1, xdh);
            unpack4(b0, xdh + 16);   // = xw[gd][:]*dinv[gd]
            float r[20];
            float ss = 0.f;
#pragma unroll
            for (int j = 0; j < 20; ++j) {
                r[j] = dv * (acc[j] + xdh[j]) + b[j];
                ss = fmaf(r[j], r[j], ss);
            }
            float inv = 1.0f / fmaxf(sqrtf(ss), 1e-12f);
            float4 o4[5];
            float* o = (float*)o4;
#pragma unroll
            for (int j = 0; j < 20; ++j) {
                float e2 = r[j] * inv;
                o[j] = e2 > 0.f ? e2 : 0.f;
            }
            float4* eo = (float4*)(embed + (size_t)gd * EM);
#pragma unroll
            for (int c = 0; c < 5; ++c) eo[c] = o4[c];
        }
    }
}

// ---------------- per-graph pool (max+mean) + final linear ----------------
__device__ inline int lbound(const int* __restrict__ batch, int key) {
    int lo = 0, hi = NN;
    while (lo < hi) {
        int mid = (lo + hi) >> 1;
        if (batch[mid] < key) lo = mid + 1; else hi = mid;
    }
    return lo;
}

__global__ void k_poolfinal(const float* __restrict__ embed, const int* __restrict__ batch,
                            const float* __restrict__ lw, const float* __restrict__ lb,
                            float* __restrict__ out) {
    __shared__ float cross[4][40];
    __shared__ float pooled[40];
    int g = blockIdx.x;
    int s0 = lbound(batch, g), s1 = lbound(batch, g + 1);
    int cnt = s1 - s0;
    float mx[EM], sm[EM];
#pragma unroll
    for (int j = 0; j < EM; ++j) { mx[j] = 0.f; sm[j] = 0.f; }
    for (int n = s0 + threadIdx.x; n < s1; n += 256) {
        const float4* e = (const float4*)(embed + (size_t)n * EM);
#pragma unroll
        for (int c = 0; c < 5; ++c) {
            float4 v = e[c];
            int j = c * 4;
            mx[j+0] = fmaxf(mx[j+0], v.x); sm[j+0] += v.x;
            mx[j+1] = fmaxf(mx[j+1], v.y); sm[j+1] += v.y;
            mx[j+2] = fmaxf(mx[j+2], v.z); sm[j+2] += v.z;
            mx[j+3] = fmaxf(mx[j+3], v.w); sm[j+3] += v.w;
        }
    }
#pragma unroll
    for (int o = 32; o > 0; o >>= 1) {
#pragma unroll
        for (int j = 0; j < EM; ++j) {
            mx[j] = fmaxf(mx[j], __shfl_xor(mx[j], o));
            sm[j] += __shfl_xor(sm[j], o);
        }
    }
    int wave = threadIdx.x >> 6, lane = threadIdx.x & 63;
    if (lane == 0) {
#pragma unroll
        for (int j = 0; j < EM; ++j) { cross[wave][j] = mx[j]; cross[wave][EM + j] = sm[j]; }
    }
    __syncthreads();
    if (threadIdx.x < 40) {
        int j = threadIdx.x;
        float v = cross[0][j];
        if (j < EM) v = fmaxf(fmaxf(v, cross[1][j]), fmaxf(cross[2][j], cross[3][j]));
        else        v = v + cross[1][j] + cross[2][j] + cross[3][j];
        if (j >= EM) v *= 1.0f / fmaxf((float)cnt, 1.0f);
        pooled[j] = v;
    }
    __syncthreads();
    if (threadIdx.x < NC) {
        int c = threadIdx.x;
        float acc = lb[c];
#pragma unroll
        for (int j = 0; j < 2 * EM; ++j) acc = fmaf(pooled[j], lw[j * NC + c], acc);
        out[g * NC + c] = acc;
    }
}

static inline size_t align_up(size_t v) { return (v + 1023) & ~(size_t)1023; }

extern "C" void kernel_launch(void* const* d_in, const int* in_sizes, int n_in,
                              void* d_out, int out_size, void* d_ws, size_t ws_size,
                              hipStream_t stream) {
    const float* x     = (const float*)d_in[0];
    const int*   ei    = (const int*)d_in[1];
    const float* ew    = (const float*)d_in[2];
    const int*   batch = (const int*)d_in[3];
    const float* W     = (const float*)d_in[4];
    const float* b     = (const float*)d_in[5];
    const float* lw    = (const float*)d_in[6];
    const float* lb    = (const float*)d_in[7];
    float* out = (float*)d_out;

    char* ws = (char*)d_ws;
    int*    gcursor = (int*)ws;    ws += align_up(4096);
    float*  dinv    = (float*)ws;  ws += align_up((size_t)NN * 4);          // 400 KB
    __half* xwhA    = (__half*)ws; ws += align_up((size_t)NN * 16 * 2);     // 3.2 MB
    __half* xwhB    = (__half*)ws; ws += align_up((size_t)NN * 4 * 2);      // 0.8 MB
    float*  embed   = (float*)ws;  ws += align_up((size_t)NN * EM * 4);     // 8 MB
    uint2*  barr    = (uint2*)ws;                                           // 28.8 MB
    unsigned long long* barr64 = (unsigned long long*)barr;

    const int* srcp = ei;
    const int* dstp = ei + NE;

    (void)hipMemsetAsync(gcursor, 0, 4096, stream);
    k_scatter<<<(NE + T - 1) / T, SBLK, 0, stream>>>(srcp, dstp, ew, gcursor, barr);
    k_degb<<<NB, 1024, 0, stream>>>(gcursor, barr, dinv);
    k_xw<<<(NN + 63) / 64, 256, 0, stream>>>(x, W, dinv, xwhA, xwhB);
    k_sortaggr<<<NB, 512, 0, stream>>>(gcursor, barr64, xwhA, xwhB, dinv, b, embed);
    k_poolfinal<<<NG, 256, 0, stream>>>(embed, batch, lw, lb, out);
}